// Round 10
// baseline (594.708 us; speedup 1.0000x reference)
//
#include <hip/hip_runtime.h>

// Problem constants
#define BN    2400   // B*N
#define NG    4      // groups
#define DIM   256

// DTYPE: inputs fp32, output fp32. Internal ws bf16.
// R10: GEMMs are LDS-BW-bound (R9 model: 73% of gen cycles = LDS traffic).
// Rule: small L2-resident operand -> direct global->register fragments;
// large operand -> LDS-staged. gen: A(qv_B,1.2MB) direct, W staged.
// proj: B(weights,4MB) direct, A(FMS/FC,39MB) staged. Everything else = R9.

typedef __attribute__((ext_vector_type(8))) short bf16x8;
typedef __attribute__((ext_vector_type(4))) short bf16x4;
typedef __attribute__((ext_vector_type(4))) float f32x4;

__device__ __forceinline__ float b2f(unsigned short u) {
    union { unsigned int i; float f; } v; v.i = ((unsigned int)u) << 16; return v.f;
}
__device__ __forceinline__ unsigned short f2b(float f) {
    union { float f; unsigned int i; } v; v.f = f;
    unsigned int x = v.i;
    return (unsigned short)((x + 0x7fffu + ((x >> 16) & 1u)) >> 16);  // RNE
}

__device__ __forceinline__ void block_stats(float s, float q, float* sRed, int tid,
                                            float inv_n, float& mean, float& istd) {
    #pragma unroll
    for (int off = 32; off > 0; off >>= 1) {
        s += __shfl_down(s, off, 64);
        q += __shfl_down(q, off, 64);
    }
    if ((tid & 63) == 0) { sRed[(tid >> 6) * 2] = s; sRed[(tid >> 6) * 2 + 1] = q; }
    __syncthreads();
    if (tid == 0) {
        float ts = 0.f, tq = 0.f;
        for (int w = 0; w < 4; ++w) { ts += sRed[2 * w]; tq += sRed[2 * w + 1]; }
        float m = ts * inv_n;
        float var = tq * inv_n - m * m;
        sRed[8] = m; sRed[9] = rsqrtf(var + 1e-5f);
    }
    __syncthreads();
    mean = sRed[8]; istd = sRed[9];
}

// ---------------------------------------------------------------------------
// Weight preps
// ---------------------------------------------------------------------------
__global__ __launch_bounds__(256) void prep_perm_kernel(
    const float* __restrict__ wA, const float* __restrict__ bA,
    unsigned short* __restrict__ oA, float* __restrict__ obA,
    const float* __restrict__ wB, const float* __restrict__ bB,
    unsigned short* __restrict__ oB, float* __restrict__ obB)
{
    const float* w = blockIdx.y ? wB : wA;
    const float* b = blockIdx.y ? bB : bA;
    unsigned short* wOut = blockIdx.y ? oB : oA;
    float* bOut = blockIdx.y ? obB : obA;

    const int row_o = blockIdx.x * 4 + (threadIdx.x >> 6);
    const int lane = threadIdx.x & 63;
    const int g = row_o >> 12, d = (row_o >> 6) & 63, c = row_o & 63;
    const int row_i = (g << 12) + c * 64 + d;
    const float4 x = *(const float4*)(w + (size_t)row_i * 256 + lane * 4);
    bf16x4 pk;
    pk[0] = (short)f2b(x.x); pk[1] = (short)f2b(x.y);
    pk[2] = (short)f2b(x.z); pk[3] = (short)f2b(x.w);
    *(bf16x4*)(wOut + (size_t)row_o * 256 + lane * 4) = pk;
    if (lane == 0) bOut[row_o] = b[row_i];
}

__global__ __launch_bounds__(256) void prep_flat_kernel(
    const float* __restrict__ a0, unsigned short* __restrict__ o0, int n0,
    const float* __restrict__ a1, unsigned short* __restrict__ o1, int n1,
    const float* __restrict__ a2, unsigned short* __restrict__ o2, int n2)
{
    const float* src; unsigned short* dst; int n;
    if (blockIdx.y == 0)      { src = a0; dst = o0; n = n0; }
    else if (blockIdx.y == 1) { src = a1; dst = o1; n = n1; }
    else                      { src = a2; dst = o2; n = n2; }
    const int idx = (blockIdx.x * 256 + threadIdx.x) * 8;
    if (idx >= n) return;
    float4 x0 = ((const float4*)(src + idx))[0];
    float4 x1 = ((const float4*)(src + idx))[1];
    bf16x8 v;
    v[0]=(short)f2b(x0.x); v[1]=(short)f2b(x0.y); v[2]=(short)f2b(x0.z); v[3]=(short)f2b(x0.w);
    v[4]=(short)f2b(x1.x); v[5]=(short)f2b(x1.y); v[6]=(short)f2b(x1.z); v[7]=(short)f2b(x1.w);
    *(bf16x8*)(dst + idx) = v;
}

__global__ __launch_bounds__(256) void copy_bias_kernel(
    const float* __restrict__ a0, float* __restrict__ o0,
    const float* __restrict__ a1, float* __restrict__ o1)
{
    const int i = blockIdx.x * 256 + threadIdx.x;
    if (blockIdx.y == 0) o0[i] = a0[i]; else o1[i] = a1[i];
}

// ---------------------------------------------------------------------------
// Generator GEMM: C = A * W^T + bias, bf16 out. 64x64 tile, 4 waves 2x2.
// A-fragments DIRECT from global (A is qv_B: 1.2MB, L2-resident; lanes read
// 64B-contiguous row segments). Only W staged via padded LDS. y-split selects
// branch 1 vs 2.
// ---------------------------------------------------------------------------
__global__ __launch_bounds__(256) void gemm_gen_kernel(
    const unsigned short* __restrict__ A,
    const unsigned short* __restrict__ W1, const float* __restrict__ b1,
    unsigned short* __restrict__ C1,
    const unsigned short* __restrict__ W2, const float* __restrict__ b2,
    unsigned short* __restrict__ C2,
    int ySplit, int M, int N, int ldK)
{
    __shared__ short sB[64][72];

    const int yb = blockIdx.y;
    const bool s2 = (yb >= ySplit);
    const unsigned short* W = s2 ? W2 : W1;
    const float* bias = s2 ? b2 : b1;
    unsigned short* C = s2 ? C2 : C1;
    const int n0 = (s2 ? yb - ySplit : yb) * 64;

    const int m0 = blockIdx.x * 64;
    const int tid = threadIdx.x;
    const int lane = tid & 63;
    const int wave = tid >> 6;
    const int l16 = lane & 15;
    const int quad = lane >> 4;
    const int wr = (wave >> 1) * 32;
    const int wc = (wave & 1) * 32;

    const int lr = tid >> 2;
    const int lc = (tid & 3) * 16;

    // A fragment row pointers (clamped; OOB rows' stores are masked in epilogue)
    int r0 = m0 + wr + l16;      if (r0 >= M) r0 = M - 1;
    int r1 = m0 + wr + 16 + l16; if (r1 >= M) r1 = M - 1;
    const unsigned short* a0p = A + (size_t)r0 * ldK + quad * 8;
    const unsigned short* a1p = A + (size_t)r1 * ldK + quad * 8;

    f32x4 acc[2][2] = {};

    for (int k0 = 0; k0 < ldK; k0 += 64) {
        {   // stage W only (N multiple of 64 -> no guard)
            const unsigned short* wp = W + (size_t)(n0 + lr) * ldK + k0 + lc;
            *(bf16x8*)(&sB[lr][lc])     = ((const bf16x8*)wp)[0];
            *(bf16x8*)(&sB[lr][lc + 8]) = ((const bf16x8*)wp)[1];
        }
        __syncthreads();
        #pragma unroll
        for (int ks = 0; ks < 64; ks += 32) {
            bf16x8 a0 = *(const bf16x8*)(a0p + k0 + ks);
            bf16x8 a1 = *(const bf16x8*)(a1p + k0 + ks);
            bf16x8 b0 = *(const bf16x8*)(&sB[wc + l16][ks + quad * 8]);
            bf16x8 b1 = *(const bf16x8*)(&sB[wc + 16 + l16][ks + quad * 8]);
            acc[0][0] = __builtin_amdgcn_mfma_f32_16x16x32_bf16(a0, b0, acc[0][0], 0, 0, 0);
            acc[0][1] = __builtin_amdgcn_mfma_f32_16x16x32_bf16(a0, b1, acc[0][1], 0, 0, 0);
            acc[1][0] = __builtin_amdgcn_mfma_f32_16x16x32_bf16(a1, b0, acc[1][0], 0, 0, 0);
            acc[1][1] = __builtin_amdgcn_mfma_f32_16x16x32_bf16(a1, b1, acc[1][1], 0, 0, 0);
        }
        __syncthreads();
    }

    #pragma unroll
    for (int s = 0; s < 2; ++s) {
        #pragma unroll
        for (int u = 0; u < 2; ++u) {
            const int col = n0 + wc + u * 16 + l16;
            const float bv = bias[col];
            #pragma unroll
            for (int r = 0; r < 4; ++r) {
                const int row = m0 + wr + s * 16 + quad * 4 + r;
                if (row < M)
                    C[(size_t)row * N + col] = f2b(acc[s][u][r] + bv);
            }
        }
    }
}

// ---------------------------------------------------------------------------
// Projection GEMM: fp32 split-K partials. 64x64 tile, 4 waves 2x2.
// B-fragments DIRECT from global (B = proj weights: 4MB, L2-resident).
// Only A (FMS/FC, 39MB) staged via padded LDS. z-split selects branch.
// ---------------------------------------------------------------------------
__global__ __launch_bounds__(256) void gemm_proj_kernel(
    const unsigned short* __restrict__ A1, const unsigned short* __restrict__ W1,
    float* __restrict__ C1,
    const unsigned short* __restrict__ A2, const unsigned short* __restrict__ W2,
    float* __restrict__ C2,
    int zSplit, int M, int N, int ldK, int kLen)
{
    __shared__ short sA[64][72];

    const int z = blockIdx.z;
    const bool s2 = (z >= zSplit);
    const int zi = s2 ? z - zSplit : z;
    const unsigned short* A = s2 ? A2 : A1;
    const unsigned short* W = s2 ? W2 : W1;
    float* C = (s2 ? C2 : C1) + (size_t)zi * M * N;

    const int m0 = blockIdx.x * 64;
    const int n0 = blockIdx.y * 64;
    const int tid = threadIdx.x;
    const int lane = tid & 63;
    const int wave = tid >> 6;
    const int l16 = lane & 15;
    const int quad = lane >> 4;
    const int wr = (wave >> 1) * 32;
    const int wc = (wave & 1) * 32;

    const int lr = tid >> 2;
    const int lc = (tid & 3) * 16;

    // B fragment row pointers (N=256, rows always valid)
    const unsigned short* b0p = W + (size_t)(n0 + wc + l16) * ldK + quad * 8;
    const unsigned short* b1p = W + (size_t)(n0 + wc + 16 + l16) * ldK + quad * 8;

    f32x4 acc[2][2] = {};

    const int kbase = zi * kLen;
    for (int k0 = kbase; k0 < kbase + kLen; k0 += 64) {
        {   // stage A only
            const int gr = m0 + lr;
            bf16x8 a0 = {}, a1 = {};
            if (gr < M) {
                const unsigned short* ap = A + (size_t)gr * ldK + k0 + lc;
                a0 = ((const bf16x8*)ap)[0];
                a1 = ((const bf16x8*)ap)[1];
            }
            *(bf16x8*)(&sA[lr][lc])     = a0;
            *(bf16x8*)(&sA[lr][lc + 8]) = a1;
        }
        __syncthreads();
        #pragma unroll
        for (int ks = 0; ks < 64; ks += 32) {
            bf16x8 a0 = *(const bf16x8*)(&sA[wr + l16][ks + quad * 8]);
            bf16x8 a1 = *(const bf16x8*)(&sA[wr + 16 + l16][ks + quad * 8]);
            bf16x8 b0 = *(const bf16x8*)(b0p + k0 + ks);
            bf16x8 b1 = *(const bf16x8*)(b1p + k0 + ks);
            acc[0][0] = __builtin_amdgcn_mfma_f32_16x16x32_bf16(a0, b0, acc[0][0], 0, 0, 0);
            acc[0][1] = __builtin_amdgcn_mfma_f32_16x16x32_bf16(a0, b1, acc[0][1], 0, 0, 0);
            acc[1][0] = __builtin_amdgcn_mfma_f32_16x16x32_bf16(a1, b0, acc[1][0], 0, 0, 0);
            acc[1][1] = __builtin_amdgcn_mfma_f32_16x16x32_bf16(a1, b1, acc[1][1], 0, 0, 0);
        }
        __syncthreads();
    }

    #pragma unroll
    for (int s = 0; s < 2; ++s) {
        #pragma unroll
        for (int u = 0; u < 2; ++u) {
            const int col = n0 + wc + u * 16 + l16;
            #pragma unroll
            for (int r = 0; r < 4; ++r) {
                const int row = m0 + wr + s * 16 + quad * 4 + r;
                if (row < M)
                    C[(size_t)row * N + col] = acc[s][u][r];
            }
        }
    }
}

// ===========================================================================
// Phase-2 device helpers (unchanged from R9; layouts verified m89/m91).
// ===========================================================================
__device__ __forceinline__ void p2_stage_feats(
    const float* fp, short (*fB)[72], int tid)
{
    const float* p = fp + tid * 8;
    float4 x0 = ((const float4*)p)[0];
    float4 x1 = ((const float4*)p)[1];
    bf16x8 v;
    v[0]=(short)f2b(x0.x); v[1]=(short)f2b(x0.y); v[2]=(short)f2b(x0.z); v[3]=(short)f2b(x0.w);
    v[4]=(short)f2b(x1.x); v[5]=(short)f2b(x1.y); v[6]=(short)f2b(x1.z); v[7]=(short)f2b(x1.w);
    *(bf16x8*)(&fB[tid >> 3][(tid & 7) * 8]) = v;
}

__device__ __forceinline__ void p2_stage_64x64(
    const unsigned short* mp, short (*T)[72], int tid)
{
    const unsigned short* p = mp + tid * 16;
    bf16x8 v0 = ((const bf16x8*)p)[0];
    bf16x8 v1 = ((const bf16x8*)p)[1];
    const int d = tid >> 2, c0 = (tid & 3) * 16;
    *(bf16x8*)(&T[d][c0])     = v0;
    *(bf16x8*)(&T[d][c0 + 8]) = v1;
}

__device__ __forceinline__ void p2_stage_32x32(
    const unsigned short* sp, short (*T)[40], int tid)
{
    *(bf16x4*)(&T[tid >> 3][(tid & 7) * 4]) = *(const bf16x4*)(sp + tid * 4);
}

__device__ __forceinline__ void p2_reg_body(
    short (*fB)[72], short (*Mt)[72], short (*sS)[40], short (*X1T)[40],
    float* sRed, unsigned short* outp, int tid)
{
    const int wave = tid >> 6, lane = tid & 63;
    const int l16 = lane & 15, quad = lane >> 4;

    f32x4 accA[2] = {};
    #pragma unroll
    for (int ks = 0; ks < 64; ks += 32) {
        bf16x8 b = *(const bf16x8*)(&Mt[wave * 16 + l16][ks + quad * 8]);
        #pragma unroll
        for (int mt = 0; mt < 2; ++mt) {
            bf16x8 a = *(const bf16x8*)(&fB[mt * 16 + l16][ks + quad * 8]);
            accA[mt] = __builtin_amdgcn_mfma_f32_16x16x32_bf16(a, b, accA[mt], 0, 0, 0);
        }
    }
    float ls = 0.f, lq = 0.f;
    #pragma unroll
    for (int mt = 0; mt < 2; ++mt)
        #pragma unroll
        for (int r = 0; r < 4; ++r) { float v = accA[mt][r]; ls += v; lq += v * v; }
    float mean, istd;
    block_stats(ls, lq, sRed, tid, 1.0f / 2048.0f, mean, istd);
    #pragma unroll
    for (int mt = 0; mt < 2; ++mt) {
        bf16x4 pk;
        #pragma unroll
        for (int r = 0; r < 4; ++r) {
            float y = (accA[mt][r] - mean) * istd;
            pk[r] = (short)f2b(y > 0.f ? y : 0.f);
        }
        *(bf16x4*)(&X1T[wave * 16 + l16][mt * 16 + quad * 4]) = pk;
    }
    __syncthreads();

    f32x4 accB[2] = {};
    {
        bf16x8 b = *(const bf16x8*)(&X1T[wave * 16 + l16][quad * 8]);
        #pragma unroll
        for (int mt = 0; mt < 2; ++mt) {
            bf16x8 a = *(const bf16x8*)(&sS[mt * 16 + l16][quad * 8]);
            accB[mt] = __builtin_amdgcn_mfma_f32_16x16x32_bf16(a, b, accB[mt], 0, 0, 0);
        }
    }
    ls = 0.f; lq = 0.f;
    #pragma unroll
    for (int mt = 0; mt < 2; ++mt)
        #pragma unroll
        for (int r = 0; r < 4; ++r) { float v = accB[mt][r]; ls += v; lq += v * v; }
    block_stats(ls, lq, sRed, tid, 1.0f / 2048.0f, mean, istd);

    const int d = wave * 16 + l16;
    #pragma unroll
    for (int mt = 0; mt < 2; ++mt)
        #pragma unroll
        for (int r = 0; r < 4; ++r) {
            float y = (accB[mt][r] - mean) * istd;
            outp[(mt * 16 + quad * 4 + r) * 64 + d] = f2b(y > 0.f ? y : 0.f);
        }
}

__device__ __forceinline__ void p2_cls_body(
    short (*fB)[72], short (*Vt)[72], short (*kw)[72], short (*vRM)[72],
    short (*vT)[40], short (*kT)[40], short (*sQ)[40], short (*sSC)[40],
    float* sKB, float* sRed, unsigned short* outp, int tid)
{
    const int wave = tid >> 6, lane = tid & 63;
    const int l16 = lane & 15, quad = lane >> 4;

    f32x4 accA[2] = {};
    #pragma unroll
    for (int ks = 0; ks < 64; ks += 32) {
        bf16x8 b = *(const bf16x8*)(&Vt[wave * 16 + l16][ks + quad * 8]);
        #pragma unroll
        for (int mt = 0; mt < 2; ++mt) {
            bf16x8 a = *(const bf16x8*)(&fB[mt * 16 + l16][ks + quad * 8]);
            accA[mt] = __builtin_amdgcn_mfma_f32_16x16x32_bf16(a, b, accA[mt], 0, 0, 0);
        }
    }
    float ls = 0.f, lq = 0.f;
    #pragma unroll
    for (int mt = 0; mt < 2; ++mt)
        #pragma unroll
        for (int r = 0; r < 4; ++r) { float v = accA[mt][r]; ls += v; lq += v * v; }
    float mean, istd;
    block_stats(ls, lq, sRed, tid, 1.0f / 2048.0f, mean, istd);
    {
        const int d = wave * 16 + l16;
        #pragma unroll
        for (int mt = 0; mt < 2; ++mt) {
            bf16x4 pk;
            #pragma unroll
            for (int r = 0; r < 4; ++r) {
                float y = (accA[mt][r] - mean) * istd;
                unsigned short u = f2b(y > 0.f ? y : 0.f);
                pk[r] = (short)u;
                vRM[mt * 16 + quad * 4 + r][d] = (short)u;
            }
            *(bf16x4*)(&vT[d][mt * 16 + quad * 4]) = pk;
        }
    }
    __syncthreads();

    {   // k[i][p] = kw[i]·v[p] + kb
        const int it = wave >> 1, pt = wave & 1;
        f32x4 accK = {};
        #pragma unroll
        for (int ks = 0; ks < 64; ks += 32) {
            bf16x8 a = *(const bf16x8*)(&kw[it * 16 + l16][ks + quad * 8]);
            bf16x8 b = *(const bf16x8*)(&vRM[pt * 16 + l16][ks + quad * 8]);
            accK = __builtin_amdgcn_mfma_f32_16x16x32_bf16(a, b, accK, 0, 0, 0);
        }
        bf16x4 pk;
        #pragma unroll
        for (int r = 0; r < 4; ++r)
            pk[r] = (short)f2b(accK[r] + sKB[it * 16 + quad * 4 + r]);
        *(bf16x4*)(&kT[pt * 16 + l16][it * 16 + quad * 4]) = pk;
    }
    __syncthreads();

    if (wave < 2) {   // logits + softmax
        f32x4 accL[2] = {};
        bf16x8 a = *(const bf16x8*)(&sQ[wave * 16 + l16][quad * 8]);
        #pragma unroll
        for (int pt = 0; pt < 2; ++pt) {
            bf16x8 b = *(const bf16x8*)(&kT[pt * 16 + l16][quad * 8]);
            accL[pt] = __builtin_amdgcn_mfma_f32_16x16x32_bf16(a, b, accL[pt], 0, 0, 0);
        }
        #pragma unroll
        for (int r = 0; r < 4; ++r) {
            float a0 = accL[0][r] * 0.125f, a1 = accL[1][r] * 0.125f;
            float mx = fmaxf(a0, a1);
            #pragma unroll
            for (int m = 1; m < 16; m <<= 1) mx = fmaxf(mx, __shfl_xor(mx, m, 64));
            a0 = __expf(a0 - mx); a1 = __expf(a1 - mx);
            float sum = a0 + a1;
            #pragma unroll
            for (int m = 1; m < 16; m <<= 1) sum += __shfl_xor(sum, m, 64);
            const float inv_s = 1.0f / sum;
            const int o = wave * 16 + quad * 4 + r;
            sSC[o][l16]      = (short)f2b(a0 * inv_s);
            sSC[o][16 + l16] = (short)f2b(a1 * inv_s);
        }
    }
    __syncthreads();

    f32x4 accB[2] = {};
    {
        bf16x8 b = *(const bf16x8*)(&vT[wave * 16 + l16][quad * 8]);
        #pragma unroll
        for (int mt = 0; mt < 2; ++mt) {
            bf16x8 a = *(const bf16x8*)(&sSC[mt * 16 + l16][quad * 8]);
            accB[mt] = __builtin_amdgcn_mfma_f32_16x16x32_bf16(a, b, accB[mt], 0, 0, 0);
        }
    }
    ls = 0.f; lq = 0.f;
    #pragma unroll
    for (int mt = 0; mt < 2; ++mt)
        #pragma unroll
        for (int r = 0; r < 4; ++r) { float v = accB[mt][r]; ls += v; lq += v * v; }
    block_stats(ls, lq, sRed, tid, 1.0f / 2048.0f, mean, istd);

    const int d = wave * 16 + l16;
    #pragma unroll
    for (int mt = 0; mt < 2; ++mt)
        #pragma unroll
        for (int r = 0; r < 4; ++r) {
            float y = (accB[mt][r] - mean) * istd;
            outp[(mt * 16 + quad * 4 + r) * 64 + d] = f2b(y > 0.f ? y : 0.f);
        }
}

__device__ __forceinline__ void p2_stage_cls(
    const unsigned short* Y2row, const float* kwp, const float* kbp, int g,
    short (*kw)[72], short (*sQ)[40], float* sKB, int tid)
{
    {
        const float* kp = kwp + (size_t)g * 2048 + tid * 8;
        float4 x0 = ((const float4*)kp)[0];
        float4 x1 = ((const float4*)kp)[1];
        bf16x8 v;
        v[0]=(short)f2b(x0.x); v[1]=(short)f2b(x0.y); v[2]=(short)f2b(x0.z); v[3]=(short)f2b(x0.w);
        v[4]=(short)f2b(x1.x); v[5]=(short)f2b(x1.y); v[6]=(short)f2b(x1.z); v[7]=(short)f2b(x1.w);
        *(bf16x8*)(&kw[tid >> 3][(tid & 7) * 8]) = v;
    }
    p2_stage_32x32(Y2row + 16384 + g * 1024, sQ, tid);
    if (tid < 32) sKB[tid] = kbp[g * 32 + tid];
}

// ---------------------------------------------------------------------------
// p2 split kernels (small-ws path)
// ---------------------------------------------------------------------------
__global__ __launch_bounds__(256) void p2_reg_kernel(
    const float* __restrict__ feats, const unsigned short* __restrict__ Y1,
    unsigned short* __restrict__ FMS)
{
    const int t = blockIdx.x, g = blockIdx.y;
    const int tid = threadIdx.x;
    __shared__ short fB[32][72];
    __shared__ short Mt[64][72];
    __shared__ short sS[32][40];
    __shared__ short X1T[64][40];
    __shared__ float sRed[16];

    p2_stage_feats(feats + (size_t)(t * NG + g) * 2048, fB, tid);
    p2_stage_64x64(Y1 + (size_t)t * 20480 + g * 4096, Mt, tid);
    p2_stage_32x32(Y1 + (size_t)t * 20480 + 16384 + g * 1024, sS, tid);
    __syncthreads();
    p2_reg_body(fB, Mt, sS, X1T, sRed, FMS + (size_t)t * 8192 + g * 2048, tid);
}

__global__ __launch_bounds__(256) void p2_cls_kernel(
    const float* __restrict__ feats, const unsigned short* __restrict__ Y2,
    const float* __restrict__ kwp, const float* __restrict__ kbp,
    unsigned short* __restrict__ FC)
{
    const int t = blockIdx.x, g = blockIdx.y;
    const int tid = threadIdx.x;
    __shared__ short fB[32][72];
    __shared__ short Vt[64][72];
    __shared__ short kw[32][72];
    __shared__ short vRM[32][72];
    __shared__ short vT[64][40];
    __shared__ short kT[32][40];
    __shared__ short sQ[32][40];
    __shared__ short sSC[32][40];
    __shared__ float sKB[32];
    __shared__ float sRed[16];

    p2_stage_feats(feats + (size_t)(t * NG + g) * 2048, fB, tid);
    p2_stage_64x64(Y2 + (size_t)t * 20480 + g * 4096, Vt, tid);
    p2_stage_cls(Y2 + (size_t)t * 20480, kwp, kbp, g, kw, sQ, sKB, tid);
    __syncthreads();
    p2_cls_body(fB, Vt, kw, vRM, vT, kT, sQ, sSC, sKB, sRed,
                FC + (size_t)t * 8192 + g * 2048, tid);
}

// ---------------------------------------------------------------------------
// p2 fused kernel (big-ws path)
// ---------------------------------------------------------------------------
__global__ __launch_bounds__(256) void p2_fused_kernel(
    const float* __restrict__ feats,
    const unsigned short* __restrict__ Y1,
    const unsigned short* __restrict__ Y2,
    const float* __restrict__ kwp, const float* __restrict__ kbp,
    unsigned short* __restrict__ FMS, unsigned short* __restrict__ FC)
{
    const int t = blockIdx.x, g = blockIdx.y;
    const int tid = threadIdx.x;
    __shared__ short fB[32][72];
    __shared__ short MtVt[64][72];
    __shared__ short XvT[64][40];
    __shared__ short sSQ[32][40];
    __shared__ short kw[32][72];
    __shared__ short vRM[32][72];
    __shared__ short kT[32][40];
    __shared__ short sSC[32][40];
    __shared__ float sKB[32];
    __shared__ float sRed[16];

    p2_stage_feats(feats + (size_t)(t * NG + g) * 2048, fB, tid);
    p2_stage_64x64(Y1 + (size_t)t * 20480 + g * 4096, MtVt, tid);
    p2_stage_32x32(Y1 + (size_t)t * 20480 + 16384 + g * 1024, sSQ, tid);
    __syncthreads();
    p2_reg_body(fB, MtVt, sSQ, XvT, sRed, FMS + (size_t)t * 8192 + g * 2048, tid);
    __syncthreads();
    p2_stage_64x64(Y2 + (size_t)t * 20480 + g * 4096, MtVt, tid);
    p2_stage_cls(Y2 + (size_t)t * 20480, kwp, kbp, g, kw, sSQ, sKB, tid);
    __syncthreads();
    p2_cls_body(fB, MtVt, kw, vRM, XvT, kT, sSQ, sSC, sKB, sRed,
                FC + (size_t)t * 8192 + g * 2048, tid);
}

// ---------------------------------------------------------------------------
// Final: reduce split-K=8 partials, residual add, affine LN over 256, fp32 out.
// ---------------------------------------------------------------------------
__global__ __launch_bounds__(256) void final_ln_kernel(
    const float* __restrict__ qv,
    const float* __restrict__ MSP, const float* __restrict__ CLP,
    const float* __restrict__ Wv_b, const float* __restrict__ Wv2_b,
    const float* __restrict__ lnA_w, const float* __restrict__ lnA_b,
    const float* __restrict__ lnB_w, const float* __restrict__ lnB_b,
    float* __restrict__ out)
{
    __shared__ float sRed[16];
    const int t = blockIdx.x;
    const int br = blockIdx.y;
    const int c = threadIdx.x;
    const float* P = br ? CLP : MSP;
    const float* bias = br ? Wv2_b : Wv_b;
    const float* lw = br ? lnB_w : lnA_w;
    const float* lb = br ? lnB_b : lnA_b;

    float x = qv[t * 256 + c] + bias[c];
    #pragma unroll
    for (int s = 0; s < 8; ++s) x += P[(size_t)s * (BN * 256) + t * 256 + c];

    float mean, istd;
    block_stats(x, x * x, sRed, c, 1.0f / 256.0f, mean, istd);
    out[(size_t)br * (BN * 256) + t * 256 + c] = (x - mean) * istd * lw[c] + lb[c];
}

// ---------------------------------------------------------------------------
extern "C" void kernel_launch(void* const* d_in, const int* in_sizes, int n_in,
                              void* d_out, int out_size, void* d_ws, size_t ws_size,
                              hipStream_t stream) {
    const float* feats = (const float*)d_in[0];
    const float* qv    = (const float*)d_in[1];
    const float* m_w   = (const float*)d_in[7];
    const float* m_b   = (const float*)d_in[8];
    const float* s_w   = (const float*)d_in[9];
    const float* s_b   = (const float*)d_in[10];
    const float* q_w   = (const float*)d_in[11];
    const float* q_b   = (const float*)d_in[12];
    const float* v_w   = (const float*)d_in[13];
    const float* v_b   = (const float*)d_in[14];
    const float* k_w   = (const float*)d_in[15];
    const float* k_b   = (const float*)d_in[16];
    const float* Wv_w  = (const float*)d_in[17];
    const float* Wv_b  = (const float*)d_in[18];
    const float* Wv2_w = (const float*)d_in[19];
    const float* Wv2_b = (const float*)d_in[20];
    const float* lnA_w = (const float*)d_in[21];
    const float* lnA_b = (const float*)d_in[22];
    const float* lnB_w = (const float*)d_in[23];
    const float* lnB_b = (const float*)d_in[24];

    char* ws = (char*)d_ws;
    const dim3 blk(256);

    if (ws_size >= 275251200ull) {
        // ===== BIG path (275.3 MB) =====
        unsigned short* Y1 = (unsigned short*)(ws);
        unsigned short* Y2 = (unsigned short*)(ws + 98304000);
        unsigned short* W1   = (unsigned short*)(ws + 196608000);
        unsigned short* W2   = (unsigned short*)(ws + 196608000 + 10485760);
        unsigned short* qv_B = (unsigned short*)(ws + 196608000 + 20971520);
        float* b1 = (float*)(ws + 196608000 + 22200320);
        float* b2 = (float*)(ws + 196608000 + 22282240);
        unsigned short* FMS = (unsigned short*)(ws + 196608000);
        unsigned short* FC  = (unsigned short*)(ws + 235929600);
        unsigned short* WvB  = (unsigned short*)(ws + 98304000);
        unsigned short* Wv2B = (unsigned short*)(ws + 98304000 + 4194304);
        float* MSP = (float*)(ws);
        float* CLP = (float*)(ws + 19660800);

        prep_perm_kernel<<<dim3(4096, 2), blk, 0, stream>>>(m_w, m_b, W1, b1,
                                                            v_w, v_b, W2, b2);
        prep_flat_kernel<<<dim3(512, 3), blk, 0, stream>>>(
            s_w, W1 + 16384 * 256, 4096 * 256,
            q_w, W2 + 16384 * 256, 4096 * 256,
            qv,  qv_B,             BN * 256);
        copy_bias_kernel<<<dim3(16, 2), blk, 0, stream>>>(s_b, b1 + 16384, q_b, b2 + 16384);
        gemm_gen_kernel<<<dim3(38, 640), blk, 0, stream>>>(
            qv_B, W1, b1, Y1, W2, b2, Y2, 320, BN, 20480, 256);
        p2_fused_kernel<<<dim3(BN, NG), blk, 0, stream>>>(
            feats, Y1, Y2, k_w, k_b, FMS, FC);
        prep_flat_kernel<<<dim3(1024, 2), blk, 0, stream>>>(
            Wv_w, WvB, 256 * 8192, Wv2_w, Wv2B, 256 * 8192, nullptr, nullptr, 0);
        gemm_proj_kernel<<<dim3(38, 4, 16), blk, 0, stream>>>(
            FMS, WvB, MSP, FC, Wv2B, CLP, 8, BN, 256, 8192, 1024);
        final_ln_kernel<<<dim3(BN, 2), blk, 0, stream>>>(
            qv, MSP, CLP, Wv_b, Wv2_b, lnA_w, lnA_b, lnB_w, lnB_b, (float*)d_out);
    } else {
        // ===== SMALL path (176.9 MB fallback) =====
        unsigned short* Y1  = (unsigned short*)(ws);
        unsigned short* FMS = (unsigned short*)(ws + 98304000);
        unsigned short* FC  = (unsigned short*)(ws + 137625600);
        unsigned short* W1   = (unsigned short*)(ws + 137625600);
        unsigned short* W2   = (unsigned short*)(ws + 137625600 + 10485760);
        unsigned short* qv_B = (unsigned short*)(ws + 137625600 + 20971520);
        float* b1 = (float*)(ws + 137625600 + 22200320);
        float* b2 = (float*)(ws + 137625600 + 22282240);
        float* MSP = (float*)(ws);
        float* CLP = (float*)(ws + 19660800);
        unsigned short* WvB  = (unsigned short*)(ws + 39321600);
        unsigned short* Wv2B = (unsigned short*)(ws + 43515904);

        prep_perm_kernel<<<dim3(4096, 2), blk, 0, stream>>>(m_w, m_b, W1, b1,
                                                            v_w, v_b, W2, b2);
        prep_flat_kernel<<<dim3(512, 3), blk, 0, stream>>>(
            s_w, W1 + 16384 * 256, 4096 * 256,
            q_w, W2 + 16384 * 256, 4096 * 256,
            qv,  qv_B,             BN * 256);
        copy_bias_kernel<<<dim3(16, 2), blk, 0, stream>>>(s_b, b1 + 16384, q_b, b2 + 16384);
        gemm_gen_kernel<<<dim3(38, 320), blk, 0, stream>>>(
            qv_B, W1, b1, Y1, W1, b1, Y1, 320, BN, 20480, 256);
        p2_reg_kernel<<<dim3(BN, NG), blk, 0, stream>>>(feats, Y1, FMS);
        gemm_gen_kernel<<<dim3(38, 320), blk, 0, stream>>>(
            qv_B, W2, b2, Y1, W2, b2, Y1, 320, BN, 20480, 256);
        p2_cls_kernel<<<dim3(BN, NG), blk, 0, stream>>>(feats, Y1, k_w, k_b, FC);
        prep_flat_kernel<<<dim3(1024, 2), blk, 0, stream>>>(
            Wv_w, WvB, 256 * 8192, Wv2_w, Wv2B, 256 * 8192, nullptr, nullptr, 0);
        gemm_proj_kernel<<<dim3(38, 4, 8), blk, 0, stream>>>(
            FMS, WvB, MSP, FMS, WvB, MSP, 8, BN, 256, 8192, 1024);
        gemm_proj_kernel<<<dim3(38, 4, 8), blk, 0, stream>>>(
            FC, Wv2B, CLP, FC, Wv2B, CLP, 8, BN, 256, 8192, 1024);
        final_ln_kernel<<<dim3(BN, 2), blk, 0, stream>>>(
            qv, MSP, CLP, Wv_b, Wv2_b, lnA_w, lnA_b, lnB_w, lnB_b, (float*)d_out);
    }
}

// Round 11
// 456.941 us; speedup vs baseline: 1.3015x; 1.3015x over previous
//
#include <hip/hip_runtime.h>

// Problem constants
#define BN    2400   // B*N
#define NG    4      // groups
#define DIM   256

// DTYPE: inputs fp32, output fp32. Internal ws bf16.
// R11: R10's direct-A gather reverted. Instead, qv is PRE-PACKED into
// MFMA-fragment-major layout (qvP[mt][kc][rg][lane]) so A-fragment loads are
// single coalesced 1KB wave transactions from an L2-hot 1.2MB buffer; sA and
// its LDS traffic deleted from the gen GEMM. Proj reverted to R9 both-staged.
// All else identical to R9 (458us best).

typedef __attribute__((ext_vector_type(8))) short bf16x8;
typedef __attribute__((ext_vector_type(4))) short bf16x4;
typedef __attribute__((ext_vector_type(4))) float f32x4;

__device__ __forceinline__ float b2f(unsigned short u) {
    union { unsigned int i; float f; } v; v.i = ((unsigned int)u) << 16; return v.f;
}
__device__ __forceinline__ unsigned short f2b(float f) {
    union { float f; unsigned int i; } v; v.f = f;
    unsigned int x = v.i;
    return (unsigned short)((x + 0x7fffu + ((x >> 16) & 1u)) >> 16);  // RNE
}

__device__ __forceinline__ void block_stats(float s, float q, float* sRed, int tid,
                                            float inv_n, float& mean, float& istd) {
    #pragma unroll
    for (int off = 32; off > 0; off >>= 1) {
        s += __shfl_down(s, off, 64);
        q += __shfl_down(q, off, 64);
    }
    if ((tid & 63) == 0) { sRed[(tid >> 6) * 2] = s; sRed[(tid >> 6) * 2 + 1] = q; }
    __syncthreads();
    if (tid == 0) {
        float ts = 0.f, tq = 0.f;
        for (int w = 0; w < 4; ++w) { ts += sRed[2 * w]; tq += sRed[2 * w + 1]; }
        float m = ts * inv_n;
        float var = tq * inv_n - m * m;
        sRed[8] = m; sRed[9] = rsqrtf(var + 1e-5f);
    }
    __syncthreads();
    mean = sRed[8]; istd = sRed[9];
}

// ---------------------------------------------------------------------------
// Weight preps
// ---------------------------------------------------------------------------
__global__ __launch_bounds__(256) void prep_perm_kernel(
    const float* __restrict__ wA, const float* __restrict__ bA,
    unsigned short* __restrict__ oA, float* __restrict__ obA,
    const float* __restrict__ wB, const float* __restrict__ bB,
    unsigned short* __restrict__ oB, float* __restrict__ obB)
{
    const float* w = blockIdx.y ? wB : wA;
    const float* b = blockIdx.y ? bB : bA;
    unsigned short* wOut = blockIdx.y ? oB : oA;
    float* bOut = blockIdx.y ? obB : obA;

    const int row_o = blockIdx.x * 4 + (threadIdx.x >> 6);
    const int lane = threadIdx.x & 63;
    const int g = row_o >> 12, d = (row_o >> 6) & 63, c = row_o & 63;
    const int row_i = (g << 12) + c * 64 + d;
    const float4 x = *(const float4*)(w + (size_t)row_i * 256 + lane * 4);
    bf16x4 pk;
    pk[0] = (short)f2b(x.x); pk[1] = (short)f2b(x.y);
    pk[2] = (short)f2b(x.z); pk[3] = (short)f2b(x.w);
    *(bf16x4*)(wOut + (size_t)row_o * 256 + lane * 4) = pk;
    if (lane == 0) bOut[row_o] = b[row_i];
}

__global__ __launch_bounds__(256) void prep_flat_kernel(
    const float* __restrict__ a0, unsigned short* __restrict__ o0, int n0,
    const float* __restrict__ a1, unsigned short* __restrict__ o1, int n1,
    const float* __restrict__ a2, unsigned short* __restrict__ o2, int n2)
{
    const float* src; unsigned short* dst; int n;
    if (blockIdx.y == 0)      { src = a0; dst = o0; n = n0; }
    else if (blockIdx.y == 1) { src = a1; dst = o1; n = n1; }
    else                      { src = a2; dst = o2; n = n2; }
    const int idx = (blockIdx.x * 256 + threadIdx.x) * 8;
    if (idx >= n) return;
    float4 x0 = ((const float4*)(src + idx))[0];
    float4 x1 = ((const float4*)(src + idx))[1];
    bf16x8 v;
    v[0]=(short)f2b(x0.x); v[1]=(short)f2b(x0.y); v[2]=(short)f2b(x0.z); v[3]=(short)f2b(x0.w);
    v[4]=(short)f2b(x1.x); v[5]=(short)f2b(x1.y); v[6]=(short)f2b(x1.z); v[7]=(short)f2b(x1.w);
    *(bf16x8*)(dst + idx) = v;
}

__global__ __launch_bounds__(256) void copy_bias_kernel(
    const float* __restrict__ a0, float* __restrict__ o0,
    const float* __restrict__ a1, float* __restrict__ o1)
{
    const int i = blockIdx.x * 256 + threadIdx.x;
    if (blockIdx.y == 0) o0[i] = a0[i]; else o1[i] = a1[i];
}

// ---------------------------------------------------------------------------
// Pack qv (fp32, BN x 256) into MFMA-A-fragment-major bf16:
// qvP[mt][kc][rg][lane][8] = qv[mt*64 + rg*16 + (lane&15)][kc*32 + (lane>>4)*8 + j]
// mt in [0,38), kc in [0,8), rg in [0,4). Rows >= BN clamp to BN-1 (epilogue masks).
// One thread = one 8-elem chunk. Total chunks = 38*8*4*64 = 77824.
// ---------------------------------------------------------------------------
__global__ __launch_bounds__(256) void prep_pack_a_kernel(
    const float* __restrict__ qv, unsigned short* __restrict__ qvP)
{
    const int idx = blockIdx.x * 256 + threadIdx.x;   // chunk index
    if (idx >= 38 * 8 * 4 * 64) return;
    const int lane = idx & 63;
    const int rg   = (idx >> 6) & 3;
    const int kc   = (idx >> 8) & 7;
    const int mt   = idx >> 11;
    int row = mt * 64 + rg * 16 + (lane & 15);
    if (row >= BN) row = BN - 1;
    const int col = kc * 32 + (lane >> 4) * 8;
    const float* p = qv + (size_t)row * 256 + col;
    float4 x0 = ((const float4*)p)[0];
    float4 x1 = ((const float4*)p)[1];
    bf16x8 v;
    v[0]=(short)f2b(x0.x); v[1]=(short)f2b(x0.y); v[2]=(short)f2b(x0.z); v[3]=(short)f2b(x0.w);
    v[4]=(short)f2b(x1.x); v[5]=(short)f2b(x1.y); v[6]=(short)f2b(x1.z); v[7]=(short)f2b(x1.w);
    *(bf16x8*)(qvP + (size_t)idx * 8) = v;
}

// ---------------------------------------------------------------------------
// Generator GEMM: C = qv * W^T + bias, bf16 out. 64x64 tile, 4 waves 2x2.
// A-fragments from the PACKED qvP (coalesced 1KB wave loads, L2-hot).
// Only W staged via padded LDS (9.2KB). y-split selects branch 1 vs 2.
// ---------------------------------------------------------------------------
__global__ __launch_bounds__(256) void gemm_gen_kernel(
    const unsigned short* __restrict__ qvP,
    const unsigned short* __restrict__ W1, const float* __restrict__ b1,
    unsigned short* __restrict__ C1,
    const unsigned short* __restrict__ W2, const float* __restrict__ b2,
    unsigned short* __restrict__ C2,
    int ySplit, int M, int N, int ldK)
{
    __shared__ short sB[64][72];

    const int yb = blockIdx.y;
    const bool s2 = (yb >= ySplit);
    const unsigned short* W = s2 ? W2 : W1;
    const float* bias = s2 ? b2 : b1;
    unsigned short* C = s2 ? C2 : C1;
    const int n0 = (s2 ? yb - ySplit : yb) * 64;

    const int m0 = blockIdx.x * 64;
    const int tid = threadIdx.x;
    const int lane = tid & 63;
    const int wave = tid >> 6;
    const int l16 = lane & 15;
    const int quad = lane >> 4;
    const int wr = (wave >> 1) * 32;
    const int wc = (wave & 1) * 32;

    const int lr = tid >> 2;
    const int lc = (tid & 3) * 16;

    // packed A base for this m-tile: qvP + mt*8*4*64*8 ushorts
    const unsigned short* aP = qvP + (size_t)blockIdx.x * (8 * 4 * 64 * 8);
    const int rg0 = (wave >> 1) * 2;   // row-group of a0; a1 = rg0+1

    f32x4 acc[2][2] = {};

    for (int k0 = 0; k0 < ldK; k0 += 64) {
        {   // stage W only (N multiple of 64 -> no guard)
            const unsigned short* wp = W + (size_t)(n0 + lr) * ldK + k0 + lc;
            *(bf16x8*)(&sB[lr][lc])     = ((const bf16x8*)wp)[0];
            *(bf16x8*)(&sB[lr][lc + 8]) = ((const bf16x8*)wp)[1];
        }
        __syncthreads();
        #pragma unroll
        for (int ks = 0; ks < 64; ks += 32) {
            const int kc = (k0 + ks) >> 5;
            const unsigned short* af = aP + ((kc * 4) * 64 + lane) * 8;
            bf16x8 a0 = *(const bf16x8*)(af + (rg0 * 64) * 8);
            bf16x8 a1 = *(const bf16x8*)(af + ((rg0 + 1) * 64) * 8);
            bf16x8 b0 = *(const bf16x8*)(&sB[wc + l16][ks + quad * 8]);
            bf16x8 b1 = *(const bf16x8*)(&sB[wc + 16 + l16][ks + quad * 8]);
            acc[0][0] = __builtin_amdgcn_mfma_f32_16x16x32_bf16(a0, b0, acc[0][0], 0, 0, 0);
            acc[0][1] = __builtin_amdgcn_mfma_f32_16x16x32_bf16(a0, b1, acc[0][1], 0, 0, 0);
            acc[1][0] = __builtin_amdgcn_mfma_f32_16x16x32_bf16(a1, b0, acc[1][0], 0, 0, 0);
            acc[1][1] = __builtin_amdgcn_mfma_f32_16x16x32_bf16(a1, b1, acc[1][1], 0, 0, 0);
        }
        __syncthreads();
    }

    #pragma unroll
    for (int s = 0; s < 2; ++s) {
        #pragma unroll
        for (int u = 0; u < 2; ++u) {
            const int col = n0 + wc + u * 16 + l16;
            const float bv = bias[col];
            #pragma unroll
            for (int r = 0; r < 4; ++r) {
                const int row = m0 + wr + s * 16 + quad * 4 + r;
                if (row < M)
                    C[(size_t)row * N + col] = f2b(acc[s][u][r] + bv);
            }
        }
    }
}

// ---------------------------------------------------------------------------
// Projection GEMM (R9 both-staged): fp32 split-K partials. 64x64 tile.
// z-split selects branch; zi indexes the K-slice.
// ---------------------------------------------------------------------------
__global__ __launch_bounds__(256) void gemm_proj_kernel(
    const unsigned short* __restrict__ A1, const unsigned short* __restrict__ W1,
    float* __restrict__ C1,
    const unsigned short* __restrict__ A2, const unsigned short* __restrict__ W2,
    float* __restrict__ C2,
    int zSplit, int M, int N, int ldK, int kLen)
{
    __shared__ short sA[64][72];
    __shared__ short sB[64][72];

    const int z = blockIdx.z;
    const bool s2 = (z >= zSplit);
    const int zi = s2 ? z - zSplit : z;
    const unsigned short* A = s2 ? A2 : A1;
    const unsigned short* W = s2 ? W2 : W1;
    float* C = (s2 ? C2 : C1) + (size_t)zi * M * N;

    const int m0 = blockIdx.x * 64;
    const int n0 = blockIdx.y * 64;
    const int tid = threadIdx.x;
    const int lane = tid & 63;
    const int wave = tid >> 6;
    const int l16 = lane & 15;
    const int quad = lane >> 4;
    const int wr = (wave >> 1) * 32;
    const int wc = (wave & 1) * 32;

    const int lr = tid >> 2;
    const int lc = (tid & 3) * 16;

    f32x4 acc[2][2] = {};

    const int kbase = zi * kLen;
    for (int k0 = kbase; k0 < kbase + kLen; k0 += 64) {
        {
            const int gr = m0 + lr;
            bf16x8 a0 = {}, a1 = {};
            if (gr < M) {
                const unsigned short* ap = A + (size_t)gr * ldK + k0 + lc;
                a0 = ((const bf16x8*)ap)[0];
                a1 = ((const bf16x8*)ap)[1];
            }
            *(bf16x8*)(&sA[lr][lc])     = a0;
            *(bf16x8*)(&sA[lr][lc + 8]) = a1;
            const unsigned short* wp = W + (size_t)(n0 + lr) * ldK + k0 + lc;
            *(bf16x8*)(&sB[lr][lc])     = ((const bf16x8*)wp)[0];
            *(bf16x8*)(&sB[lr][lc + 8]) = ((const bf16x8*)wp)[1];
        }
        __syncthreads();
        #pragma unroll
        for (int ks = 0; ks < 64; ks += 32) {
            bf16x8 a0 = *(const bf16x8*)(&sA[wr + l16][ks + quad * 8]);
            bf16x8 a1 = *(const bf16x8*)(&sA[wr + 16 + l16][ks + quad * 8]);
            bf16x8 b0 = *(const bf16x8*)(&sB[wc + l16][ks + quad * 8]);
            bf16x8 b1 = *(const bf16x8*)(&sB[wc + 16 + l16][ks + quad * 8]);
            acc[0][0] = __builtin_amdgcn_mfma_f32_16x16x32_bf16(a0, b0, acc[0][0], 0, 0, 0);
            acc[0][1] = __builtin_amdgcn_mfma_f32_16x16x32_bf16(a0, b1, acc[0][1], 0, 0, 0);
            acc[1][0] = __builtin_amdgcn_mfma_f32_16x16x32_bf16(a1, b0, acc[1][0], 0, 0, 0);
            acc[1][1] = __builtin_amdgcn_mfma_f32_16x16x32_bf16(a1, b1, acc[1][1], 0, 0, 0);
        }
        __syncthreads();
    }

    #pragma unroll
    for (int s = 0; s < 2; ++s) {
        #pragma unroll
        for (int u = 0; u < 2; ++u) {
            const int col = n0 + wc + u * 16 + l16;
            #pragma unroll
            for (int r = 0; r < 4; ++r) {
                const int row = m0 + wr + s * 16 + quad * 4 + r;
                if (row < M)
                    C[(size_t)row * N + col] = acc[s][u][r];
            }
        }
    }
}

// ===========================================================================
// Phase-2 device helpers (unchanged from R9; layouts verified m89/m91).
// ===========================================================================
__device__ __forceinline__ void p2_stage_feats(
    const float* fp, short (*fB)[72], int tid)
{
    const float* p = fp + tid * 8;
    float4 x0 = ((const float4*)p)[0];
    float4 x1 = ((const float4*)p)[1];
    bf16x8 v;
    v[0]=(short)f2b(x0.x); v[1]=(short)f2b(x0.y); v[2]=(short)f2b(x0.z); v[3]=(short)f2b(x0.w);
    v[4]=(short)f2b(x1.x); v[5]=(short)f2b(x1.y); v[6]=(short)f2b(x1.z); v[7]=(short)f2b(x1.w);
    *(bf16x8*)(&fB[tid >> 3][(tid & 7) * 8]) = v;
}

__device__ __forceinline__ void p2_stage_64x64(
    const unsigned short* mp, short (*T)[72], int tid)
{
    const unsigned short* p = mp + tid * 16;
    bf16x8 v0 = ((const bf16x8*)p)[0];
    bf16x8 v1 = ((const bf16x8*)p)[1];
    const int d = tid >> 2, c0 = (tid & 3) * 16;
    *(bf16x8*)(&T[d][c0])     = v0;
    *(bf16x8*)(&T[d][c0 + 8]) = v1;
}

__device__ __forceinline__ void p2_stage_32x32(
    const unsigned short* sp, short (*T)[40], int tid)
{
    *(bf16x4*)(&T[tid >> 3][(tid & 7) * 4]) = *(const bf16x4*)(sp + tid * 4);
}

__device__ __forceinline__ void p2_reg_body(
    short (*fB)[72], short (*Mt)[72], short (*sS)[40], short (*X1T)[40],
    float* sRed, unsigned short* outp, int tid)
{
    const int wave = tid >> 6, lane = tid & 63;
    const int l16 = lane & 15, quad = lane >> 4;

    f32x4 accA[2] = {};
    #pragma unroll
    for (int ks = 0; ks < 64; ks += 32) {
        bf16x8 b = *(const bf16x8*)(&Mt[wave * 16 + l16][ks + quad * 8]);
        #pragma unroll
        for (int mt = 0; mt < 2; ++mt) {
            bf16x8 a = *(const bf16x8*)(&fB[mt * 16 + l16][ks + quad * 8]);
            accA[mt] = __builtin_amdgcn_mfma_f32_16x16x32_bf16(a, b, accA[mt], 0, 0, 0);
        }
    }
    float ls = 0.f, lq = 0.f;
    #pragma unroll
    for (int mt = 0; mt < 2; ++mt)
        #pragma unroll
        for (int r = 0; r < 4; ++r) { float v = accA[mt][r]; ls += v; lq += v * v; }
    float mean, istd;
    block_stats(ls, lq, sRed, tid, 1.0f / 2048.0f, mean, istd);
    #pragma unroll
    for (int mt = 0; mt < 2; ++mt) {
        bf16x4 pk;
        #pragma unroll
        for (int r = 0; r < 4; ++r) {
            float y = (accA[mt][r] - mean) * istd;
            pk[r] = (short)f2b(y > 0.f ? y : 0.f);
        }
        *(bf16x4*)(&X1T[wave * 16 + l16][mt * 16 + quad * 4]) = pk;
    }
    __syncthreads();

    f32x4 accB[2] = {};
    {
        bf16x8 b = *(const bf16x8*)(&X1T[wave * 16 + l16][quad * 8]);
        #pragma unroll
        for (int mt = 0; mt < 2; ++mt) {
            bf16x8 a = *(const bf16x8*)(&sS[mt * 16 + l16][quad * 8]);
            accB[mt] = __builtin_amdgcn_mfma_f32_16x16x32_bf16(a, b, accB[mt], 0, 0, 0);
        }
    }
    ls = 0.f; lq = 0.f;
    #pragma unroll
    for (int mt = 0; mt < 2; ++mt)
        #pragma unroll
        for (int r = 0; r < 4; ++r) { float v = accB[mt][r]; ls += v; lq += v * v; }
    block_stats(ls, lq, sRed, tid, 1.0f / 2048.0f, mean, istd);

    const int d = wave * 16 + l16;
    #pragma unroll
    for (int mt = 0; mt < 2; ++mt)
        #pragma unroll
        for (int r = 0; r < 4; ++r) {
            float y = (accB[mt][r] - mean) * istd;
            outp[(mt * 16 + quad * 4 + r) * 64 + d] = f2b(y > 0.f ? y : 0.f);
        }
}

__device__ __forceinline__ void p2_cls_body(
    short (*fB)[72], short (*Vt)[72], short (*kw)[72], short (*vRM)[72],
    short (*vT)[40], short (*kT)[40], short (*sQ)[40], short (*sSC)[40],
    float* sKB, float* sRed, unsigned short* outp, int tid)
{
    const int wave = tid >> 6, lane = tid & 63;
    const int l16 = lane & 15, quad = lane >> 4;

    f32x4 accA[2] = {};
    #pragma unroll
    for (int ks = 0; ks < 64; ks += 32) {
        bf16x8 b = *(const bf16x8*)(&Vt[wave * 16 + l16][ks + quad * 8]);
        #pragma unroll
        for (int mt = 0; mt < 2; ++mt) {
            bf16x8 a = *(const bf16x8*)(&fB[mt * 16 + l16][ks + quad * 8]);
            accA[mt] = __builtin_amdgcn_mfma_f32_16x16x32_bf16(a, b, accA[mt], 0, 0, 0);
        }
    }
    float ls = 0.f, lq = 0.f;
    #pragma unroll
    for (int mt = 0; mt < 2; ++mt)
        #pragma unroll
        for (int r = 0; r < 4; ++r) { float v = accA[mt][r]; ls += v; lq += v * v; }
    float mean, istd;
    block_stats(ls, lq, sRed, tid, 1.0f / 2048.0f, mean, istd);
    {
        const int d = wave * 16 + l16;
        #pragma unroll
        for (int mt = 0; mt < 2; ++mt) {
            bf16x4 pk;
            #pragma unroll
            for (int r = 0; r < 4; ++r) {
                float y = (accA[mt][r] - mean) * istd;
                unsigned short u = f2b(y > 0.f ? y : 0.f);
                pk[r] = (short)u;
                vRM[mt * 16 + quad * 4 + r][d] = (short)u;
            }
            *(bf16x4*)(&vT[d][mt * 16 + quad * 4]) = pk;
        }
    }
    __syncthreads();

    {   // k[i][p] = kw[i]·v[p] + kb
        const int it = wave >> 1, pt = wave & 1;
        f32x4 accK = {};
        #pragma unroll
        for (int ks = 0; ks < 64; ks += 32) {
            bf16x8 a = *(const bf16x8*)(&kw[it * 16 + l16][ks + quad * 8]);
            bf16x8 b = *(const bf16x8*)(&vRM[pt * 16 + l16][ks + quad * 8]);
            accK = __builtin_amdgcn_mfma_f32_16x16x32_bf16(a, b, accK, 0, 0, 0);
        }
        bf16x4 pk;
        #pragma unroll
        for (int r = 0; r < 4; ++r)
            pk[r] = (short)f2b(accK[r] + sKB[it * 16 + quad * 4 + r]);
        *(bf16x4*)(&kT[pt * 16 + l16][it * 16 + quad * 4]) = pk;
    }
    __syncthreads();

    if (wave < 2) {   // logits + softmax
        f32x4 accL[2] = {};
        bf16x8 a = *(const bf16x8*)(&sQ[wave * 16 + l16][quad * 8]);
        #pragma unroll
        for (int pt = 0; pt < 2; ++pt) {
            bf16x8 b = *(const bf16x8*)(&kT[pt * 16 + l16][quad * 8]);
            accL[pt] = __builtin_amdgcn_mfma_f32_16x16x32_bf16(a, b, accL[pt], 0, 0, 0);
        }
        #pragma unroll
        for (int r = 0; r < 4; ++r) {
            float a0 = accL[0][r] * 0.125f, a1 = accL[1][r] * 0.125f;
            float mx = fmaxf(a0, a1);
            #pragma unroll
            for (int m = 1; m < 16; m <<= 1) mx = fmaxf(mx, __shfl_xor(mx, m, 64));
            a0 = __expf(a0 - mx); a1 = __expf(a1 - mx);
            float sum = a0 + a1;
            #pragma unroll
            for (int m = 1; m < 16; m <<= 1) sum += __shfl_xor(sum, m, 64);
            const float inv_s = 1.0f / sum;
            const int o = wave * 16 + quad * 4 + r;
            sSC[o][l16]      = (short)f2b(a0 * inv_s);
            sSC[o][16 + l16] = (short)f2b(a1 * inv_s);
        }
    }
    __syncthreads();

    f32x4 accB[2] = {};
    {
        bf16x8 b = *(const bf16x8*)(&vT[wave * 16 + l16][quad * 8]);
        #pragma unroll
        for (int mt = 0; mt < 2; ++mt) {
            bf16x8 a = *(const bf16x8*)(&sSC[mt * 16 + l16][quad * 8]);
            accB[mt] = __builtin_amdgcn_mfma_f32_16x16x32_bf16(a, b, accB[mt], 0, 0, 0);
        }
    }
    ls = 0.f; lq = 0.f;
    #pragma unroll
    for (int mt = 0; mt < 2; ++mt)
        #pragma unroll
        for (int r = 0; r < 4; ++r) { float v = accB[mt][r]; ls += v; lq += v * v; }
    block_stats(ls, lq, sRed, tid, 1.0f / 2048.0f, mean, istd);

    const int d = wave * 16 + l16;
    #pragma unroll
    for (int mt = 0; mt < 2; ++mt)
        #pragma unroll
        for (int r = 0; r < 4; ++r) {
            float y = (accB[mt][r] - mean) * istd;
            outp[(mt * 16 + quad * 4 + r) * 64 + d] = f2b(y > 0.f ? y : 0.f);
        }
}

__device__ __forceinline__ void p2_stage_cls(
    const unsigned short* Y2row, const float* kwp, const float* kbp, int g,
    short (*kw)[72], short (*sQ)[40], float* sKB, int tid)
{
    {
        const float* kp = kwp + (size_t)g * 2048 + tid * 8;
        float4 x0 = ((const float4*)kp)[0];
        float4 x1 = ((const float4*)kp)[1];
        bf16x8 v;
        v[0]=(short)f2b(x0.x); v[1]=(short)f2b(x0.y); v[2]=(short)f2b(x0.z); v[3]=(short)f2b(x0.w);
        v[4]=(short)f2b(x1.x); v[5]=(short)f2b(x1.y); v[6]=(short)f2b(x1.z); v[7]=(short)f2b(x1.w);
        *(bf16x8*)(&kw[tid >> 3][(tid & 7) * 8]) = v;
    }
    p2_stage_32x32(Y2row + 16384 + g * 1024, sQ, tid);
    if (tid < 32) sKB[tid] = kbp[g * 32 + tid];
}

// ---------------------------------------------------------------------------
// p2 split kernels (small-ws path)
// ---------------------------------------------------------------------------
__global__ __launch_bounds__(256) void p2_reg_kernel(
    const float* __restrict__ feats, const unsigned short* __restrict__ Y1,
    unsigned short* __restrict__ FMS)
{
    const int t = blockIdx.x, g = blockIdx.y;
    const int tid = threadIdx.x;
    __shared__ short fB[32][72];
    __shared__ short Mt[64][72];
    __shared__ short sS[32][40];
    __shared__ short X1T[64][40];
    __shared__ float sRed[16];

    p2_stage_feats(feats + (size_t)(t * NG + g) * 2048, fB, tid);
    p2_stage_64x64(Y1 + (size_t)t * 20480 + g * 4096, Mt, tid);
    p2_stage_32x32(Y1 + (size_t)t * 20480 + 16384 + g * 1024, sS, tid);
    __syncthreads();
    p2_reg_body(fB, Mt, sS, X1T, sRed, FMS + (size_t)t * 8192 + g * 2048, tid);
}

__global__ __launch_bounds__(256) void p2_cls_kernel(
    const float* __restrict__ feats, const unsigned short* __restrict__ Y2,
    const float* __restrict__ kwp, const float* __restrict__ kbp,
    unsigned short* __restrict__ FC)
{
    const int t = blockIdx.x, g = blockIdx.y;
    const int tid = threadIdx.x;
    __shared__ short fB[32][72];
    __shared__ short Vt[64][72];
    __shared__ short kw[32][72];
    __shared__ short vRM[32][72];
    __shared__ short vT[64][40];
    __shared__ short kT[32][40];
    __shared__ short sQ[32][40];
    __shared__ short sSC[32][40];
    __shared__ float sKB[32];
    __shared__ float sRed[16];

    p2_stage_feats(feats + (size_t)(t * NG + g) * 2048, fB, tid);
    p2_stage_64x64(Y2 + (size_t)t * 20480 + g * 4096, Vt, tid);
    p2_stage_cls(Y2 + (size_t)t * 20480, kwp, kbp, g, kw, sQ, sKB, tid);
    __syncthreads();
    p2_cls_body(fB, Vt, kw, vRM, vT, kT, sQ, sSC, sKB, sRed,
                FC + (size_t)t * 8192 + g * 2048, tid);
}

// ---------------------------------------------------------------------------
// p2 fused kernel (big-ws path)
// ---------------------------------------------------------------------------
__global__ __launch_bounds__(256) void p2_fused_kernel(
    const float* __restrict__ feats,
    const unsigned short* __restrict__ Y1,
    const unsigned short* __restrict__ Y2,
    const float* __restrict__ kwp, const float* __restrict__ kbp,
    unsigned short* __restrict__ FMS, unsigned short* __restrict__ FC)
{
    const int t = blockIdx.x, g = blockIdx.y;
    const int tid = threadIdx.x;
    __shared__ short fB[32][72];
    __shared__ short MtVt[64][72];
    __shared__ short XvT[64][40];
    __shared__ short sSQ[32][40];
    __shared__ short kw[32][72];
    __shared__ short vRM[32][72];
    __shared__ short kT[32][40];
    __shared__ short sSC[32][40];
    __shared__ float sKB[32];
    __shared__ float sRed[16];

    p2_stage_feats(feats + (size_t)(t * NG + g) * 2048, fB, tid);
    p2_stage_64x64(Y1 + (size_t)t * 20480 + g * 4096, MtVt, tid);
    p2_stage_32x32(Y1 + (size_t)t * 20480 + 16384 + g * 1024, sSQ, tid);
    __syncthreads();
    p2_reg_body(fB, MtVt, sSQ, XvT, sRed, FMS + (size_t)t * 8192 + g * 2048, tid);
    __syncthreads();
    p2_stage_64x64(Y2 + (size_t)t * 20480 + g * 4096, MtVt, tid);
    p2_stage_cls(Y2 + (size_t)t * 20480, kwp, kbp, g, kw, sSQ, sKB, tid);
    __syncthreads();
    p2_cls_body(fB, MtVt, kw, vRM, XvT, kT, sSQ, sSC, sKB, sRed,
                FC + (size_t)t * 8192 + g * 2048, tid);
}

// ---------------------------------------------------------------------------
// Final: reduce split-K=8 partials, residual add, affine LN over 256, fp32 out.
// ---------------------------------------------------------------------------
__global__ __launch_bounds__(256) void final_ln_kernel(
    const float* __restrict__ qv,
    const float* __restrict__ MSP, const float* __restrict__ CLP,
    const float* __restrict__ Wv_b, const float* __restrict__ Wv2_b,
    const float* __restrict__ lnA_w, const float* __restrict__ lnA_b,
    const float* __restrict__ lnB_w, const float* __restrict__ lnB_b,
    float* __restrict__ out)
{
    __shared__ float sRed[16];
    const int t = blockIdx.x;
    const int br = blockIdx.y;
    const int c = threadIdx.x;
    const float* P = br ? CLP : MSP;
    const float* bias = br ? Wv2_b : Wv_b;
    const float* lw = br ? lnB_w : lnA_w;
    const float* lb = br ? lnB_b : lnA_b;

    float x = qv[t * 256 + c] + bias[c];
    #pragma unroll
    for (int s = 0; s < 8; ++s) x += P[(size_t)s * (BN * 256) + t * 256 + c];

    float mean, istd;
    block_stats(x, x * x, sRed, c, 1.0f / 256.0f, mean, istd);
    out[(size_t)br * (BN * 256) + t * 256 + c] = (x - mean) * istd * lw[c] + lb[c];
}

// ---------------------------------------------------------------------------
extern "C" void kernel_launch(void* const* d_in, const int* in_sizes, int n_in,
                              void* d_out, int out_size, void* d_ws, size_t ws_size,
                              hipStream_t stream) {
    const float* feats = (const float*)d_in[0];
    const float* qv    = (const float*)d_in[1];
    const float* m_w   = (const float*)d_in[7];
    const float* m_b   = (const float*)d_in[8];
    const float* s_w   = (const float*)d_in[9];
    const float* s_b   = (const float*)d_in[10];
    const float* q_w   = (const float*)d_in[11];
    const float* q_b   = (const float*)d_in[12];
    const float* v_w   = (const float*)d_in[13];
    const float* v_b   = (const float*)d_in[14];
    const float* k_w   = (const float*)d_in[15];
    const float* k_b   = (const float*)d_in[16];
    const float* Wv_w  = (const float*)d_in[17];
    const float* Wv_b  = (const float*)d_in[18];
    const float* Wv2_w = (const float*)d_in[19];
    const float* Wv2_b = (const float*)d_in[20];
    const float* lnA_w = (const float*)d_in[21];
    const float* lnA_b = (const float*)d_in[22];
    const float* lnB_w = (const float*)d_in[23];
    const float* lnB_b = (const float*)d_in[24];

    char* ws = (char*)d_ws;
    const dim3 blk(256);

    if (ws_size >= 275251200ull) {
        // ===== BIG path (275.3 MB) =====
        unsigned short* Y1 = (unsigned short*)(ws);
        unsigned short* Y2 = (unsigned short*)(ws + 98304000);
        unsigned short* W1   = (unsigned short*)(ws + 196608000);
        unsigned short* W2   = (unsigned short*)(ws + 196608000 + 10485760);
        unsigned short* qvP  = (unsigned short*)(ws + 196608000 + 20971520);  // 1,245,184 B
        float* b1 = (float*)(ws + 196608000 + 22216704);
        float* b2 = (float*)(ws + 196608000 + 22298624);
        unsigned short* FMS = (unsigned short*)(ws + 196608000);
        unsigned short* FC  = (unsigned short*)(ws + 235929600);
        unsigned short* WvB  = (unsigned short*)(ws + 98304000);
        unsigned short* Wv2B = (unsigned short*)(ws + 98304000 + 4194304);
        float* MSP = (float*)(ws);
        float* CLP = (float*)(ws + 19660800);

        prep_perm_kernel<<<dim3(4096, 2), blk, 0, stream>>>(m_w, m_b, W1, b1,
                                                            v_w, v_b, W2, b2);
        prep_flat_kernel<<<dim3(512, 2), blk, 0, stream>>>(
            s_w, W1 + 16384 * 256, 4096 * 256,
            q_w, W2 + 16384 * 256, 4096 * 256,
            nullptr, nullptr, 0);
        prep_pack_a_kernel<<<304, blk, 0, stream>>>(qv, qvP);
        copy_bias_kernel<<<dim3(16, 2), blk, 0, stream>>>(s_b, b1 + 16384, q_b, b2 + 16384);
        gemm_gen_kernel<<<dim3(38, 640), blk, 0, stream>>>(
            qvP, W1, b1, Y1, W2, b2, Y2, 320, BN, 20480, 256);
        p2_fused_kernel<<<dim3(BN, NG), blk, 0, stream>>>(
            feats, Y1, Y2, k_w, k_b, FMS, FC);
        prep_flat_kernel<<<dim3(1024, 2), blk, 0, stream>>>(
            Wv_w, WvB, 256 * 8192, Wv2_w, Wv2B, 256 * 8192, nullptr, nullptr, 0);
        gemm_proj_kernel<<<dim3(38, 4, 16), blk, 0, stream>>>(
            FMS, WvB, MSP, FC, Wv2B, CLP, 8, BN, 256, 8192, 1024);
        final_ln_kernel<<<dim3(BN, 2), blk, 0, stream>>>(
            qv, MSP, CLP, Wv_b, Wv2_b, lnA_w, lnA_b, lnB_w, lnB_b, (float*)d_out);
    } else {
        // ===== SMALL path (176.9 MB fallback) =====
        unsigned short* Y1  = (unsigned short*)(ws);
        unsigned short* FMS = (unsigned short*)(ws + 98304000);
        unsigned short* FC  = (unsigned short*)(ws + 137625600);
        unsigned short* W1   = (unsigned short*)(ws + 137625600);
        unsigned short* W2   = (unsigned short*)(ws + 137625600 + 10485760);
        unsigned short* qvP  = (unsigned short*)(ws + 137625600 + 20971520);
        float* b1 = (float*)(ws + 137625600 + 22216704);
        float* b2 = (float*)(ws + 137625600 + 22298624);
        float* MSP = (float*)(ws);
        float* CLP = (float*)(ws + 19660800);
        unsigned short* WvB  = (unsigned short*)(ws + 39321600);
        unsigned short* Wv2B = (unsigned short*)(ws + 43515904);

        prep_perm_kernel<<<dim3(4096, 2), blk, 0, stream>>>(m_w, m_b, W1, b1,
                                                            v_w, v_b, W2, b2);
        prep_flat_kernel<<<dim3(512, 2), blk, 0, stream>>>(
            s_w, W1 + 16384 * 256, 4096 * 256,
            q_w, W2 + 16384 * 256, 4096 * 256,
            nullptr, nullptr, 0);
        prep_pack_a_kernel<<<304, blk, 0, stream>>>(qv, qvP);
        copy_bias_kernel<<<dim3(16, 2), blk, 0, stream>>>(s_b, b1 + 16384, q_b, b2 + 16384);
        gemm_gen_kernel<<<dim3(38, 320), blk, 0, stream>>>(
            qvP, W1, b1, Y1, W1, b1, Y1, 320, BN, 20480, 256);
        p2_reg_kernel<<<dim3(BN, NG), blk, 0, stream>>>(feats, Y1, FMS);
        gemm_gen_kernel<<<dim3(38, 320), blk, 0, stream>>>(
            qvP, W2, b2, Y1, W2, b2, Y1, 320, BN, 20480, 256);
        p2_cls_kernel<<<dim3(BN, NG), blk, 0, stream>>>(feats, Y1, k_w, k_b, FC);
        prep_flat_kernel<<<dim3(1024, 2), blk, 0, stream>>>(
            Wv_w, WvB, 256 * 8192, Wv2_w, Wv2B, 256 * 8192, nullptr, nullptr, 0);
        gemm_proj_kernel<<<dim3(38, 4, 8), blk, 0, stream>>>(
            FMS, WvB, MSP, FMS, WvB, MSP, 8, BN, 256, 8192, 1024);
        gemm_proj_kernel<<<dim3(38, 4, 8), blk, 0, stream>>>(
            FC, Wv2B, CLP, FC, Wv2B, CLP, 8, BN, 256, 8192, 1024);
        final_ln_kernel<<<dim3(BN, 2), blk, 0, stream>>>(
            qv, MSP, CLP, Wv_b, Wv2_b, lnA_w, lnA_b, lnB_w, lnB_b, (float*)d_out);
    }
}